// Round 1
// baseline (899.776 us; speedup 1.0000x reference)
//
#include <hip/hip_runtime.h>
#include <stdint.h>

typedef short short8 __attribute__((ext_vector_type(8)));
typedef float float4v __attribute__((ext_vector_type(4)));

__device__ __forceinline__ uint16_t f2bf(float f){
  union { float f; uint32_t u; } v; v.f = f;
  uint32_t u = v.u;
  u += 0x7fffu + ((u >> 16) & 1u);
  return (uint16_t)(u >> 16);
}
__device__ __forceinline__ float bf2f(uint16_t h){
  union { uint32_t u; float f; } v; v.u = ((uint32_t)h) << 16;
  return v.f;
}

// ---------- weight prep: fp32 OIHW * scale -> bf16, layout [cb][kb][tap][co64][ci32], pre-swizzled ----------
__global__ __launch_bounds__(256) void prep_w(const float* __restrict__ w,
                                              const float* __restrict__ s,
                                              uint16_t* __restrict__ dst, int C){
  int idx = blockIdx.x * 256 + threadIdx.x;
  int total = C * C * 9;
  if (idx >= total) return;
  int tap = idx % 9;
  int t   = idx / 9;
  int ci  = t % C;
  int co  = t / C;
  float val = w[idx] * s[co];
  int KB = C >> 5;
  int cb = co >> 6, col = co & 63, kb = ci >> 5, cil = ci & 31;
  uint32_t blk  = (uint32_t)(cb * KB + kb) * 9u + (uint32_t)tap;
  uint32_t byte = (uint32_t)(col * 64 + cil * 2);
  byte ^= (uint32_t)((col & 7) << 4);                 // same swizzle as conv LDS reads
  *(uint16_t*)((char*)dst + (size_t)blk * 4096 + byte) = f2bf(val);
}

// ---------- pad + fp32->bf16: X[B][C][H][W] -> Xp[B][C][H+2][W+2] (zero border) ----------
template<int C, int H>
__global__ __launch_bounds__(256) void pad_in(const float* __restrict__ x, uint16_t* __restrict__ xp){
  constexpr int W = H, Hp = H + 2, Wp = W + 2;
  int idx = blockIdx.x * 256 + threadIdx.x;
  int total = 8 * C * Hp * Wp;
  if (idx >= total) return;
  int wp = idx % Wp; int t = idx / Wp;
  int hp = t % Hp;   int bc = t / Hp;
  uint16_t v = 0;
  if (hp > 0 && hp < Hp - 1 && wp > 0 && wp < Wp - 1)
    v = f2bf(x[(size_t)bc * H * W + (size_t)(hp - 1) * W + (wp - 1)]);
  xp[idx] = v;
}

// ---------- zero only the border ring of a padded buffer ----------
template<int C, int H>
__global__ __launch_bounds__(256) void zero_border(uint16_t* __restrict__ yp){
  constexpr int W = H, Hp = H + 2, Wp = W + 2;
  constexpr int NB = 2 * Wp + 2 * (Hp - 2);
  int idx = blockIdx.x * 256 + threadIdx.x;
  int total = 8 * C * NB;
  if (idx >= total) return;
  int j = idx % NB; int bc = idx / NB;
  int h, w;
  if (j < 2 * Wp) { h = (j < Wp) ? 0 : (Hp - 1); w = j % Wp; }
  else { int j2 = j - 2 * Wp; h = 1 + (j2 % (Hp - 2)); w = (j2 < (Hp - 2)) ? 0 : (Wp - 1); }
  yp[((size_t)bc * Hp + h) * Wp + w] = 0;
}

// ---------- 3x3 conv (pad=1) + bias + relu, bf16 in/out, MFMA 16x16x32 ----------
// tile: 64 co x (4h x 40w) spatial, KC=32, halo-shared LDS across the 9 taps.
template<int C, int H, bool PADOUT>
__global__ __launch_bounds__(256, 2) void conv3(const uint16_t* __restrict__ xp,
                                                const uint16_t* __restrict__ wgt,
                                                const float* __restrict__ bias,
                                                uint16_t* __restrict__ out){
  constexpr int W = H, Hp = H + 2, Wp = W + 2;
  constexpr int TH = 4, TW = 40;
  constexpr int KB = C / 32, CO_BLKS = C / 64, HT = H / TH, WT = W / TW;
  constexpr int HALO = (TH + 2) * (TW + 2);       // 252
  __shared__ uint16_t lds_in[HALO * 32];          // [sp252][ci32], swizzled, 16128 B
  __shared__ uint16_t lds_w[9 * 64 * 32];         // [tap][co64][ci32], swizzled, 36864 B

  const int tid  = threadIdx.x;
  const int lane = tid & 63, wave = tid >> 6;
  const int wm = wave >> 1, wn = wave & 1;
  const int l15 = lane & 15, khi = lane >> 4;

  int bx = blockIdx.x;
  const int cb = bx % CO_BLKS; bx /= CO_BLKS;
  const int wt = bx % WT;      bx /= WT;
  const int ht = bx % HT;
  const int b  = bx / HT;
  const int h0 = ht * TH, w0 = wt * TW;

  // per-lane invariants
  uint32_t baseA[2];
#pragma unroll
  for (int mi = 0; mi < 2; ++mi){
    int co_l = wm * 32 + mi * 16 + l15;
    baseA[mi] = (uint32_t)(co_l * 64 + khi * 16) ^ (uint32_t)((co_l & 7) << 4);
  }
  int th_f[5], tw_f[5], sp_base[5];
#pragma unroll
  for (int ni = 0; ni < 5; ++ni){
    int col16 = wn * 80 + ni * 16 + l15;
    th_f[ni] = col16 / 40;
    tw_f[ni] = col16 % 40;
    sp_base[ni] = th_f[ni] * 42 + tw_f[ni];
  }
  int shh = 0, sww = 0;
  if (tid < HALO) { shh = tid / 42; sww = tid % 42; }

  float4v acc[2][5];
#pragma unroll
  for (int mi = 0; mi < 2; ++mi)
#pragma unroll
    for (int ni = 0; ni < 5; ++ni)
      acc[mi][ni] = (float4v){0.f, 0.f, 0.f, 0.f};

  const uint16_t* wblk = wgt + (size_t)cb * KB * 9 * 2048;  // elements
  const char* lw = (const char*)lds_w;
  const char* li = (const char*)lds_in;

  for (int kb = 0; kb < KB; ++kb){
    if (kb) __syncthreads();
    // ---- stage weights: linear copy (pre-swizzled by prep_w) ----
    {
      const short8* gsrc = (const short8*)(wblk + (size_t)kb * 9 * 2048);
      short8* ldst = (short8*)lds_w;
      short8 wv[9];
#pragma unroll
      for (int k = 0; k < 9; ++k) wv[k] = gsrc[k * 256 + tid];
#pragma unroll
      for (int k = 0; k < 9; ++k) ldst[k * 256 + tid] = wv[k];
    }
    // ---- stage input halo: gather 8 ci per task, vector LDS write (swizzled) ----
    if (tid < HALO){
      const uint16_t* src = xp + ((size_t)(b * C + kb * 32) * Hp + (h0 + shh)) * Wp + (w0 + sww);
      short8 v[4];
#pragma unroll
      for (int k = 0; k < 4; ++k)
#pragma unroll
        for (int j = 0; j < 8; ++j)
          v[k][j] = (short)src[(size_t)(k * 8 + j) * (Hp * Wp)];
#pragma unroll
      for (int k = 0; k < 4; ++k){
        uint32_t byte = ((uint32_t)(tid * 64 + k * 16)) ^ ((uint32_t)(tid & 7) << 4);
        *(short8*)((char*)lds_in + byte) = v[k];
      }
    }
    __syncthreads();
    // ---- 9 taps x MFMA ----
#pragma unroll
    for (int dh = 0; dh < 3; ++dh){
#pragma unroll
      for (int dw = 0; dw < 3; ++dw){
        const int tap = dh * 3 + dw;
        short8 fa[2];
#pragma unroll
        for (int mi = 0; mi < 2; ++mi)
          fa[mi] = *(const short8*)(lw + tap * 4096 + baseA[mi]);
#pragma unroll
        for (int ni = 0; ni < 5; ++ni){
          int sp = sp_base[ni] + dh * 42 + dw;
          uint32_t byte = (uint32_t)(sp * 64 + khi * 16) ^ (uint32_t)((sp & 7) << 4);
          short8 fb = *(const short8*)(li + byte);
#pragma unroll
          for (int mi = 0; mi < 2; ++mi)
            acc[mi][ni] = __builtin_amdgcn_mfma_f32_16x16x32_bf16(fa[mi], fb, acc[mi][ni], 0, 0, 0);
        }
      }
    }
  }
  // ---- epilogue: bias + relu + bf16 store ----
#pragma unroll
  for (int mi = 0; mi < 2; ++mi){
#pragma unroll
    for (int r = 0; r < 4; ++r){
      const int co = cb * 64 + wm * 32 + mi * 16 + khi * 4 + r;
      const float bv = bias[co];
#pragma unroll
      for (int ni = 0; ni < 5; ++ni){
        float v = fmaxf(acc[mi][ni][r] + bv, 0.0f);
        const int hh = h0 + th_f[ni], ww = w0 + tw_f[ni];
        if (PADOUT)
          out[((size_t)(b * C + co) * Hp + (hh + 1)) * Wp + (ww + 1)] = f2bf(v);
        else
          out[((size_t)(b * C + co) * H + hh) * W + ww] = f2bf(v);
      }
    }
  }
}

// ---------- final: 1x1 conv (5ch) + bias + anchor decode + sigmoid -> d_out slice ----------
template<int C, int H, int OFF, int STRIDE>
__global__ __launch_bounds__(256) void head_final(const uint16_t* __restrict__ y2,
                                                  const float* __restrict__ wf,
                                                  const float* __restrict__ bfp,
                                                  float* __restrict__ outp){
  constexpr int W = H, HW = H * W, S = 33600;
  int idx = blockIdx.x * 256 + threadIdx.x;
  if (idx >= 8 * HW) return;
  const int b = idx / HW, sp = idx % HW;
  float a0 = bfp[0], a1 = bfp[1], a2 = bfp[2], a3 = bfp[3], a4 = bfp[4];
  const uint16_t* src = y2 + (size_t)b * C * HW + sp;
  for (int ci = 0; ci < C; ++ci){
    float v = bf2f(src[(size_t)ci * HW]);
    a0 += v * wf[0 * C + ci];
    a1 += v * wf[1 * C + ci];
    a2 += v * wf[2 * C + ci];
    a3 += v * wf[3 * C + ci];
    a4 += v * wf[4 * C + ci];
  }
  const float ax = (float)(sp % W) + 0.5f;
  const float ay = (float)(sp / W) + 0.5f;
  const float o0 = (ax + 0.5f * (a2 - a0)) * (float)STRIDE;
  const float o1 = (ay + 0.5f * (a3 - a1)) * (float)STRIDE;
  const float o2 = (a0 + a2) * (float)STRIDE;
  const float o3 = (a1 + a3) * (float)STRIDE;
  const float o4 = 1.0f / (1.0f + expf(-a4));
  float* ob = outp + (size_t)b * 5 * S + OFF + sp;
  ob[0 * S] = o0; ob[1 * S] = o1; ob[2 * S] = o2; ob[3 * S] = o3; ob[4 * S] = o4;
}

// ---------- per-head driver ----------
template<int C, int H, int OFF, int STRIDE>
static void run_head(const float* x, const uint16_t* W1, const float* b1,
                     const uint16_t* W2, const float* b2,
                     const float* wf, const float* bfp,
                     uint16_t* A, uint16_t* Bb, float* out, hipStream_t stream){
  constexpr int Hp = H + 2, Wp = H + 2;
  {
    int total = 8 * C * Hp * Wp;
    pad_in<C, H><<<(total + 255) / 256, 256, 0, stream>>>(x, A);
  }
  {
    constexpr int NB = 2 * Wp + 2 * (Hp - 2);
    int total = 8 * C * NB;
    zero_border<C, H><<<(total + 255) / 256, 256, 0, stream>>>(Bb);
  }
  constexpr int GRID = (C / 64) * (H / 40) * (H / 4) * 8;
  conv3<C, H, true ><<<GRID, 256, 0, stream>>>(A,  W1, b1, Bb);
  conv3<C, H, false><<<GRID, 256, 0, stream>>>(Bb, W2, b2, A);
  {
    int total = 8 * H * H;
    head_final<C, H, OFF, STRIDE><<<(total + 255) / 256, 256, 0, stream>>>(A, wf, bfp, out);
  }
}

extern "C" void kernel_launch(void* const* d_in, const int* in_sizes, int n_in,
                              void* d_out, int out_size, void* d_ws, size_t ws_size,
                              hipStream_t stream){
  (void)in_sizes; (void)n_in; (void)out_size;
  const float* p3 = (const float*)d_in[0];
  const float* p4 = (const float*)d_in[1];
  const float* p5 = (const float*)d_in[2];
  const float *w1[3], *s1[3], *b1[3], *w2[3], *s2[3], *b2[3], *wf[3], *bfp[3];
  for (int h = 0; h < 3; ++h){
    const int base = 3 + h * 8;
    w1[h]  = (const float*)d_in[base + 0];
    s1[h]  = (const float*)d_in[base + 1];
    b1[h]  = (const float*)d_in[base + 2];
    w2[h]  = (const float*)d_in[base + 3];
    s2[h]  = (const float*)d_in[base + 4];
    b2[h]  = (const float*)d_in[base + 5];
    wf[h]  = (const float*)d_in[base + 6];
    bfp[h] = (const float*)d_in[base + 7];
  }
  static const int Cs[3] = {128, 256, 512};
  size_t woff[6]; size_t off = 0;
  for (int h = 0; h < 3; ++h)
    for (int c = 0; c < 2; ++c){ woff[h * 2 + c] = off; off += (size_t)9 * Cs[h] * Cs[h] * 2; }
  const size_t regA = (size_t)8 * 128 * 162 * 162 * 2;   // 53,747,712 B (largest padded tensor)
  const size_t offA = (off + 4095) & ~(size_t)4095;
  const size_t offB = offA + regA;
  const size_t need = offB + regA;
  if (ws_size < need) return;  // workspace too small -> fail verification cleanly

  char* ws = (char*)d_ws;
  uint16_t* Wb[6];
  for (int i = 0; i < 6; ++i) Wb[i] = (uint16_t*)(ws + woff[i]);
  uint16_t* A  = (uint16_t*)(ws + offA);
  uint16_t* Bb = (uint16_t*)(ws + offB);
  float* out = (float*)d_out;

  for (int h = 0; h < 3; ++h){
    const int total = 9 * Cs[h] * Cs[h];
    prep_w<<<(total + 255) / 256, 256, 0, stream>>>(w1[h], s1[h], Wb[h * 2 + 0], Cs[h]);
    prep_w<<<(total + 255) / 256, 256, 0, stream>>>(w2[h], s2[h], Wb[h * 2 + 1], Cs[h]);
  }
  run_head<128, 160,     0,  8>(p3, Wb[0], b1[0], Wb[1], b2[0], wf[0], bfp[0], A, Bb, out, stream);
  run_head<256,  80, 25600, 16>(p4, Wb[2], b1[1], Wb[3], b2[1], wf[1], bfp[1], A, Bb, out, stream);
  run_head<512,  40, 32000, 32>(p5, Wb[4], b1[2], Wb[5], b2[2], wf[2], bfp[2], A, Bb, out, stream);
}

// Round 3
// 848.110 us; speedup vs baseline: 1.0609x; 1.0609x over previous
//
#include <hip/hip_runtime.h>
#include <stdint.h>

typedef short short8 __attribute__((ext_vector_type(8)));
typedef float f32x16 __attribute__((ext_vector_type(16)));

template<int I> struct IC { static constexpr int value = I; };

__device__ __forceinline__ uint16_t f2bf(float f){
  union{float f;uint32_t u;}v; v.f=f;
  uint32_t u=v.u; u += 0x7fffu + ((u>>16)&1u);
  return (uint16_t)(u>>16);
}
__device__ __forceinline__ float bf2f(uint16_t h){
  union{uint32_t u;float f;}v; v.u=((uint32_t)h)<<16; return v.f;
}

__device__ __forceinline__ void gl_lds16(const void* g, void* l){
  __builtin_amdgcn_global_load_lds((__attribute__((address_space(1))) const void*)g,
                                   (__attribute__((address_space(3))) void*)l, 16, 0, 0);
}

// ---------------- weight prep: OIHW fp32 * scale -> bf16 fragment layout ----------------
// layout: [f=co/32][kb=ci/32][tap][kk=(ci>>4)&1][lane][8 ci], lane = (co&31) | (((ci>>3)&1)<<5)
__global__ __launch_bounds__(256) void prep_w(const float* __restrict__ w,
                                              const float* __restrict__ s,
                                              uint16_t* __restrict__ dst, int C){
  int idx = blockIdx.x*256 + threadIdx.x;
  int total = C*C*9;
  if (idx >= total) return;
  int tap = idx % 9; int t = idx/9;
  int ci = t % C; int co = t / C;
  float val = w[idx]*s[co];
  int KB = C>>5;
  int f = co>>5;
  int lane = (co&31) | (((ci>>3)&1)<<5);
  int kk = (ci>>4)&1, kb = ci>>5, j = ci&7;
  size_t off = ((((size_t)(f*KB + kb)*9 + tap)*2 + kk)*64 + lane)*8 + j;
  dst[off] = f2bf(val);
}

// ---------------- pad + convert: NCHW fp32 -> padded chunked bf16 [b][kb][Hp][Wp][ci32] swizzled ----------------
template<int C,int H>
__global__ __launch_bounds__(256) void pad_in(const float* __restrict__ x, uint16_t* __restrict__ xp){
  constexpr int W=H, Hp=H+2, Wp=W+2, KB=C/32;
  int idx = blockIdx.x*256 + threadIdx.x;
  int total = 8*KB*Hp*Wp;
  if (idx >= total) return;
  int w = idx % Wp; int t2 = idx / Wp;
  int h = t2 % Hp;  int bk = t2 / Hp;
  const uint32_t key = (uint32_t)((w&7)<<4);
  char* dst = (char*)xp;
  size_t cbyte = (size_t)idx*64;
  if (h==0 || h==Hp-1 || w==0 || w==Wp-1){
    uint4 z = {0,0,0,0};
#pragma unroll
    for (int q=0;q<4;++q) *(uint4*)(dst + ((cbyte + (uint32_t)(q*16)) ^ key)) = z;
  } else {
    const int b = bk/KB, kb = bk - b*KB;
    const float* src = x + (((size_t)(b*C + kb*32)*H + (h-1))*W + (w-1));
#pragma unroll
    for (int q=0;q<4;++q){
      uint16_t tmp[8];
#pragma unroll
      for (int j=0;j<8;++j) tmp[j] = f2bf(src[(size_t)(q*8+j)*(H*W)]);
      *(uint4*)(dst + ((cbyte + (uint32_t)(q*16)) ^ key)) = *(uint4*)tmp;
    }
  }
}

// ---------------- zero border ring of a padded chunked buffer ----------------
template<int C,int H>
__global__ __launch_bounds__(256) void zero_border(uint16_t* __restrict__ yp){
  constexpr int Hp=H+2, Wp=H+2, KB=C/32;
  constexpr int NB = 2*Wp + 2*(Hp-2);
  int idx = blockIdx.x*256 + threadIdx.x;
  int total = 8*KB*NB;
  if (idx >= total) return;
  int j = idx % NB; int bk = idx / NB;
  int h, w;
  if (j < 2*Wp){ h = (j<Wp)?0:(Hp-1); w = j%Wp; }
  else { int j2 = j - 2*Wp; h = 1 + (j2 % (Hp-2)); w = (j2 < (Hp-2))?0:(Wp-1); }
  size_t chunk = ((size_t)bk*Hp + h)*Wp + w;
  const uint32_t key = (uint32_t)((w&7)<<4);
  uint4 z = {0,0,0,0};
  char* dst = (char*)yp;
#pragma unroll
  for (int q=0;q<4;++q) *(uint4*)(dst + ((chunk*64 + (uint32_t)(q*16)) ^ key)) = z;
}

// ---------------- 3x3 conv + bias + relu, 32x32x16 MFMA, weights via registers, dbuf LDS halo ----------------
// block: 128co x 320sp (TH=8 x TW=40), 4 waves, wave = 64co x 160sp = 2x5 frags of 32x32
template<int C,int H,bool PADOUT>
__device__ __forceinline__ void conv_body(int lbid,
    const uint16_t* __restrict__ in, const uint16_t* __restrict__ wq,
    const float* __restrict__ bias, uint16_t* __restrict__ out, char* lds)
{
  constexpr int W=H, Hp=H+2, Wp=W+2, KB=C/32, TW=40, TH=8;
  constexpr int COB=128;
  constexpr int R=TH+2, BUF=R*3072, NT=R*3, WAVES=4;
  const int tid = threadIdx.x, lane = tid&63, wave = tid>>6;
  const int wm = wave>>1, wn = wave&1;
  const int l31 = lane&31, h5 = lane>>5;

  int t = lbid;
  const int cb = t % (C/COB); t /= (C/COB);
  const int wt = t % (W/TW);  t /= (W/TW);
  const int ht = t % (H/TH);
  const int b  = t / (H/TH);
  const int h0 = ht*TH, w0 = wt*TW;
  const int cbCO = cb*(COB/32);

  // per-lane invariant LDS read addresses. Swizzle key bits [6:4] must be XORed
  // with the FULL (col*64 + q*16) field; the kk=1 (q+=2) address is addrB ^ 32.
  int addrB[5][3];
#pragma unroll
  for (int ni=0; ni<5; ++ni){
    int s = wn*160 + ni*32 + l31;
    int th = s/40, tw = s - th*40;
#pragma unroll
    for (int dw=0; dw<3; ++dw){
      int col = tw + dw;
      addrB[ni][dw] = th*3072 + ((col*64 + h5*16) ^ ((col&7)<<4));
    }
  }

  // marching weight pointers (2 co-frags per wave), +2048 B per tap
  const char* wp[2];
#pragma unroll
  for (int mi=0; mi<2; ++mi){
    int f = cbCO + wm*2 + mi;
    wp[mi] = (const char*)wq + (size_t)f * ((size_t)KB*9*2*1024) + lane*16;
  }

  f32x16 acc[2][5];
#pragma unroll
  for (int mi=0;mi<2;++mi)
#pragma unroll
    for (int ni=0;ni<5;++ni)
#pragma unroll
      for (int e=0;e<16;++e) acc[mi][ni][e] = 0.f;

  auto STAGE = [&](int bi, int kb){
    const char* src = (const char*)(in + ((size_t)(b*KB + kb)*Hp + h0)*((size_t)Wp*32) + (size_t)w0*32);
    for (int tt = wave; tt < NT; tt += WAVES){
      int r = tt/3, k = tt - r*3;
      char* l = lds + bi*BUF + r*3072 + k*1024;
      const char* g = src + (size_t)r*(Wp*64) + k*1024 + lane*16;
      if (k < 2 || lane < 40) gl_lds16(g, l);
    }
  };

  auto COMPUTE = [&](auto BC){
    constexpr int BI = decltype(BC)::value;
    const char* lb = lds + BI*BUF;
    short8 wc[2][2], wnx[2][2];
#pragma unroll
    for (int mi=0;mi<2;++mi){
      wc[mi][0] = *(const short8*)(wp[mi]);
      wc[mi][1] = *(const short8*)(wp[mi] + 1024);
      wp[mi] += 2048;
    }
#pragma unroll
    for (int tap=0; tap<9; ++tap){
      const int dh = tap/3, dw = tap - dh*3;
      if (tap < 8){
#pragma unroll
        for (int mi=0;mi<2;++mi){
          wnx[mi][0] = *(const short8*)(wp[mi]);
          wnx[mi][1] = *(const short8*)(wp[mi] + 1024);
          wp[mi] += 2048;
        }
      }
#pragma unroll
      for (int ni=0; ni<5; ++ni){
        const int a0 = addrB[ni][dw] + dh*3072;
        short8 b0 = *(const short8*)(lb + a0);
        short8 b1 = *(const short8*)(lb + (a0 ^ 32));
        acc[0][ni] = __builtin_amdgcn_mfma_f32_32x32x16_bf16(wc[0][0], b0, acc[0][ni], 0,0,0);
        acc[1][ni] = __builtin_amdgcn_mfma_f32_32x32x16_bf16(wc[1][0], b0, acc[1][ni], 0,0,0);
        acc[0][ni] = __builtin_amdgcn_mfma_f32_32x32x16_bf16(wc[0][1], b1, acc[0][ni], 0,0,0);
        acc[1][ni] = __builtin_amdgcn_mfma_f32_32x32x16_bf16(wc[1][1], b1, acc[1][ni], 0,0,0);
      }
      if (tap < 8){
#pragma unroll
        for (int mi=0;mi<2;++mi){ wc[mi][0]=wnx[mi][0]; wc[mi][1]=wnx[mi][1]; }
      }
    }
  };

  STAGE(0, 0);
  __syncthreads();
#pragma unroll 1
  for (int kb = 0; kb < KB; kb += 2){
    STAGE(1, kb+1);            // issue next-tile loads, then compute current
    COMPUTE(IC<0>{});
    __syncthreads();
    if (kb+2 < KB) STAGE(0, kb+2);
    COMPUTE(IC<1>{});
    __syncthreads();
  }

  // epilogue: bias + relu + packed 8B swizzled chunk stores
#pragma unroll
  for (int mi=0; mi<2; ++mi){
    const int kbo = cbCO + wm*2 + mi;
#pragma unroll
    for (int ni=0; ni<5; ++ni){
      const int s = wn*160 + ni*32 + l31;
      const int th = s/40, tw = s - th*40;
      size_t chunk; uint32_t key;
      if (PADOUT){
        const int hh = h0+th+1, ww = w0+tw+1;
        chunk = ((size_t)(b*KB + kbo)*Hp + hh)*Wp + ww;
        key = (uint32_t)((ww&7)<<4);
      } else {
        const int hh = h0+th, ww = w0+tw;
        chunk = ((size_t)(b*KB + kbo)*H + hh)*W + ww;
        key = (uint32_t)((ww&7)<<4);
      }
      char* ob = (char*)out;
#pragma unroll
      for (int q=0; q<4; ++q){
        const int cob = kbo*32 + q*8 + h5*4;
        float v0 = fmaxf(acc[mi][ni][4*q+0] + bias[cob+0], 0.f);
        float v1 = fmaxf(acc[mi][ni][4*q+1] + bias[cob+1], 0.f);
        float v2 = fmaxf(acc[mi][ni][4*q+2] + bias[cob+2], 0.f);
        float v3 = fmaxf(acc[mi][ni][4*q+3] + bias[cob+3], 0.f);
        uint2 dd;
        dd.x = (uint32_t)f2bf(v0) | ((uint32_t)f2bf(v1)<<16);
        dd.y = (uint32_t)f2bf(v2) | ((uint32_t)f2bf(v3)<<16);
        *(uint2*)(ob + ((chunk*64 + (uint32_t)(q*16 + h5*8)) ^ key)) = dd;
      }
    }
  }
}

template<bool PADOUT>
__global__ __launch_bounds__(256, 2) void conv_all(int b45, int b34,
    const uint16_t* in5, const uint16_t* wq5, const float* bi5, uint16_t* o5,
    const uint16_t* in4, const uint16_t* wq4, const float* bi4, uint16_t* o4,
    const uint16_t* in3, const uint16_t* wq3, const float* bi3, uint16_t* o3)
{
  __shared__ __align__(16) char lds[61440];
  const int bid = blockIdx.x;
  if (bid < b45)      conv_body<512, 40, PADOUT>(bid,       in5, wq5, bi5, o5, lds);
  else if (bid < b34) conv_body<256, 80, PADOUT>(bid - b45, in4, wq4, bi4, o4, lds);
  else                conv_body<128,160, PADOUT>(bid - b34, in3, wq3, bi3, o3, lds);
}

// ---------------- final: 1x1 conv (5ch) + decode + sigmoid ----------------
template<int C,int H,int OFF,int STRIDE>
__global__ __launch_bounds__(256) void head_final(const uint16_t* __restrict__ y,
    const float* __restrict__ wf, const float* __restrict__ bfp, float* __restrict__ outp)
{
  constexpr int W=H, HW=H*W, KBo=C/32, S=33600;
  int idx = blockIdx.x*256 + threadIdx.x;
  if (idx >= 8*HW) return;
  const int b = idx/HW, sp = idx - b*HW;
  const int w = sp % W;
  const uint32_t key = (uint32_t)((w&7)<<4);
  float a0=bfp[0], a1=bfp[1], a2=bfp[2], a3=bfp[3], a4=bfp[4];
  const char* yb = (const char*)y;
  for (int kb=0; kb<KBo; ++kb){
    size_t cbyte = ((size_t)(b*KBo + kb)*HW + sp)*64;
#pragma unroll
    for (int q=0; q<4; ++q){
      uint4 u = *(const uint4*)(yb + ((cbyte + (uint32_t)(q*16)) ^ key));
      const uint16_t* pv = (const uint16_t*)&u;
#pragma unroll
      for (int j=0; j<8; ++j){
        float v = bf2f(pv[j]);
        int ci = kb*32 + q*8 + j;
        a0 += v*wf[0*C+ci]; a1 += v*wf[1*C+ci]; a2 += v*wf[2*C+ci];
        a3 += v*wf[3*C+ci]; a4 += v*wf[4*C+ci];
      }
    }
  }
  const float ax = (float)(sp % W) + 0.5f;
  const float ay = (float)(sp / W) + 0.5f;
  const float o0 = (ax + 0.5f*(a2-a0)) * (float)STRIDE;
  const float o1 = (ay + 0.5f*(a3-a1)) * (float)STRIDE;
  const float o2 = (a0+a2) * (float)STRIDE;
  const float o3 = (a1+a3) * (float)STRIDE;
  const float o4 = 1.0f/(1.0f + expf(-a4));
  float* ob = outp + (size_t)b*5*S + OFF + sp;
  ob[0*S]=o0; ob[1*S]=o1; ob[2*S]=o2; ob[3*S]=o3; ob[4*S]=o4;
}

extern "C" void kernel_launch(void* const* d_in, const int* in_sizes, int n_in,
                              void* d_out, int out_size, void* d_ws, size_t ws_size,
                              hipStream_t stream){
  (void)in_sizes; (void)n_in; (void)out_size;
  const float* x[3] = {(const float*)d_in[0], (const float*)d_in[1], (const float*)d_in[2]};
  const float *w1[3],*s1[3],*b1[3],*w2[3],*s2[3],*b2[3],*wf[3],*bfp[3];
  for (int h=0; h<3; ++h){
    const int base = 3 + h*8;
    w1[h]=(const float*)d_in[base+0]; s1[h]=(const float*)d_in[base+1];
    b1[h]=(const float*)d_in[base+2]; w2[h]=(const float*)d_in[base+3];
    s2[h]=(const float*)d_in[base+4]; b2[h]=(const float*)d_in[base+5];
    wf[h]=(const float*)d_in[base+6]; bfp[h]=(const float*)d_in[base+7];
  }
  // h index: 0=p3(C128,H160), 1=p4(C256,H80), 2=p5(C512,H40)
  static const int   Cs[3] = {128, 256, 512};
  static const size_t Wb[3] = {294912, 1179648, 4718592};          // bytes per conv weight blob
  static const size_t Ab[3] = {53747712, 27541504, 14450688};      // padded chunked buffer bytes
  static const int   NB[3] = {640, 320, 160};                      // conv grid blocks per head
  float* out = (float*)d_out;
  char* ws = (char*)d_ws;

  // fused layout
  size_t off = 0; size_t wOff[3][2];
  for (int h=0; h<3; ++h) for (int c=0; c<2; ++c){ wOff[h][c]=off; off += Wb[h]; }
  off = (off + 255) & ~(size_t)255;
  size_t aOff[3], bOff[3];
  for (int h=0; h<3; ++h){ aOff[h]=off; off += Ab[h]; }
  for (int h=0; h<3; ++h){ bOff[h]=off; off += Ab[h]; }
  const size_t fusedNeed = off;

  const size_t seqA = (2*4718592 + 255) & ~(size_t)255;
  const size_t seqB = seqA + 53747712;
  const size_t seqNeed = seqB + 53747712;

  if (ws_size >= fusedNeed){
    // ---- fused: all heads per stage ----
    for (int h=0; h<3; ++h){
      int tot = 9*Cs[h]*Cs[h];
      prep_w<<<(tot+255)/256, 256, 0, stream>>>(w1[h], s1[h], (uint16_t*)(ws+wOff[h][0]), Cs[h]);
      prep_w<<<(tot+255)/256, 256, 0, stream>>>(w2[h], s2[h], (uint16_t*)(ws+wOff[h][1]), Cs[h]);
    }
    pad_in<128,160><<<3281, 256, 0, stream>>>(x[0], (uint16_t*)(ws+aOff[0]));
    pad_in<256, 80><<<1681, 256, 0, stream>>>(x[1], (uint16_t*)(ws+aOff[1]));
    pad_in<512, 40><<< 882, 256, 0, stream>>>(x[2], (uint16_t*)(ws+aOff[2]));
    zero_border<128,160><<<81, 256, 0, stream>>>((uint16_t*)(ws+bOff[0]));
    zero_border<256, 80><<<81, 256, 0, stream>>>((uint16_t*)(ws+bOff[1]));
    zero_border<512, 40><<<82, 256, 0, stream>>>((uint16_t*)(ws+bOff[2]));
    const int b45 = NB[2], b34 = NB[2]+NB[1], grid = NB[2]+NB[1]+NB[0];
    conv_all<true><<<grid, 256, 0, stream>>>(b45, b34,
      (const uint16_t*)(ws+aOff[2]), (const uint16_t*)(ws+wOff[2][0]), b1[2], (uint16_t*)(ws+bOff[2]),
      (const uint16_t*)(ws+aOff[1]), (const uint16_t*)(ws+wOff[1][0]), b1[1], (uint16_t*)(ws+bOff[1]),
      (const uint16_t*)(ws+aOff[0]), (const uint16_t*)(ws+wOff[0][0]), b1[0], (uint16_t*)(ws+bOff[0]));
    conv_all<false><<<grid, 256, 0, stream>>>(b45, b34,
      (const uint16_t*)(ws+bOff[2]), (const uint16_t*)(ws+wOff[2][1]), b2[2], (uint16_t*)(ws+aOff[2]),
      (const uint16_t*)(ws+bOff[1]), (const uint16_t*)(ws+wOff[1][1]), b2[1], (uint16_t*)(ws+aOff[1]),
      (const uint16_t*)(ws+bOff[0]), (const uint16_t*)(ws+wOff[0][1]), b2[0], (uint16_t*)(ws+aOff[0]));
    head_final<128,160,     0,  8><<<800, 256, 0, stream>>>((const uint16_t*)(ws+aOff[0]), wf[0], bfp[0], out);
    head_final<256, 80, 25600, 16><<<200, 256, 0, stream>>>((const uint16_t*)(ws+aOff[1]), wf[1], bfp[1], out);
    head_final<512, 40, 32000, 32><<< 50, 256, 0, stream>>>((const uint16_t*)(ws+aOff[2]), wf[2], bfp[2], out);
  } else {
    if (ws_size < seqNeed) return;   // cannot run
    // ---- sequential per head (workspace-constrained fallback) ----
    uint16_t* W1p = (uint16_t*)(ws + 0);
    uint16_t* W2p = (uint16_t*)(ws + 4718592);
    uint16_t* A   = (uint16_t*)(ws + seqA);
    uint16_t* B   = (uint16_t*)(ws + seqB);
    for (int h=0; h<3; ++h){
      int tot = 9*Cs[h]*Cs[h];
      prep_w<<<(tot+255)/256, 256, 0, stream>>>(w1[h], s1[h], W1p, Cs[h]);
      prep_w<<<(tot+255)/256, 256, 0, stream>>>(w2[h], s2[h], W2p, Cs[h]);
      int grid = NB[h];
      int b45, b34;
      if (h==2){ b45=grid; b34=grid; } else if (h==1){ b45=0; b34=grid; } else { b45=0; b34=0; }
      if (h==0){
        pad_in<128,160><<<3281,256,0,stream>>>(x[0], A);
        zero_border<128,160><<<81,256,0,stream>>>(B);
      } else if (h==1){
        pad_in<256,80><<<1681,256,0,stream>>>(x[1], A);
        zero_border<256,80><<<81,256,0,stream>>>(B);
      } else {
        pad_in<512,40><<<882,256,0,stream>>>(x[2], A);
        zero_border<512,40><<<82,256,0,stream>>>(B);
      }
      conv_all<true><<<grid, 256, 0, stream>>>(b45, b34,
        A, W1p, b1[h], B,  A, W1p, b1[h], B,  A, W1p, b1[h], B);
      conv_all<false><<<grid, 256, 0, stream>>>(b45, b34,
        B, W2p, b2[h], A,  B, W2p, b2[h], A,  B, W2p, b2[h], A);
      if (h==0)      head_final<128,160,     0,  8><<<800,256,0,stream>>>(A, wf[0], bfp[0], out);
      else if (h==1) head_final<256, 80, 25600, 16><<<200,256,0,stream>>>(A, wf[1], bfp[1], out);
      else           head_final<512, 40, 32000, 32><<< 50,256,0,stream>>>(A, wf[2], bfp[2], out);
    }
  }
}

// Round 4
// 707.940 us; speedup vs baseline: 1.2710x; 1.1980x over previous
//
#include <hip/hip_runtime.h>
#include <stdint.h>

typedef short short8 __attribute__((ext_vector_type(8)));
typedef float f32x4 __attribute__((ext_vector_type(4)));

template<int I> struct IC { static constexpr int value = I; };

__device__ __forceinline__ uint16_t f2bf(float f){
  union{float f;uint32_t u;}v; v.f=f;
  uint32_t u=v.u; u += 0x7fffu + ((u>>16)&1u);
  return (uint16_t)(u>>16);
}
__device__ __forceinline__ float bf2f(uint16_t h){
  union{uint32_t u;float f;}v; v.u=((uint32_t)h)<<16; return v.f;
}

__device__ __forceinline__ void gl_lds16(const void* g, void* l){
  __builtin_amdgcn_global_load_lds((__attribute__((address_space(1))) const void*)g,
                                   (__attribute__((address_space(3))) void*)l, 16, 0, 0);
}

// ---------------- weight prep (coalesced LDS transpose) ----------------
// out layout: [kb][tap][f16 over C][lane64][j8] bf16, 1024B per (kb,tap,f16) frag.
// lane = (co&15) | ((ci8_group)<<4), j = ci&7  (A-frag of mfma_f32_16x16x32_bf16)
__global__ __launch_bounds__(256) void prep_w2(const float* __restrict__ w,
                                               const float* __restrict__ s,
                                               uint16_t* __restrict__ dst, int C){
  __shared__ float lds[16][289];
  const int F16 = C >> 4;
  const int tid = threadIdx.x;
  const int f16 = blockIdx.x % F16;
  const int kb  = blockIdx.x / F16;
  // read 16 co-rows x 288 floats (ci-window 32 x 9 taps), coalesced
#pragma unroll
  for (int i = 0; i < 18; ++i){
    int idx = tid + i*256;                       // 0..4607
    int co  = idx / 288, rem = idx - co*288;
    lds[co][rem] = w[(size_t)(f16*16 + co)*C*9 + (size_t)kb*288 + rem];
  }
  __syncthreads();
  const int lane = tid >> 2;                     // 0..63
  const int jj   = (tid & 3)*2;                  // 0,2,4,6
  const int co_l = lane & 15, oct = lane >> 4;
  const int ci0  = oct*8 + jj;
  const float sc = s[f16*16 + co_l];
  uint32_t* db = (uint32_t*)dst;
#pragma unroll
  for (int tap = 0; tap < 9; ++tap){
    float v0 = lds[co_l][(ci0  )*9 + tap] * sc;
    float v1 = lds[co_l][(ci0+1)*9 + tap] * sc;
    uint32_t pk = (uint32_t)f2bf(v0) | ((uint32_t)f2bf(v1) << 16);
    size_t o = (((size_t)(kb*9 + tap)*F16 + f16)*512 + (size_t)lane*8 + jj) >> 1;
    db[o] = pk;
  }
}

// ---------------- pad + convert: NCHW fp32 -> padded chunked bf16 [b][kb][Hp][Wp][ci32] swizzled ----------------
template<int C,int H>
__global__ __launch_bounds__(256) void pad_in(const float* __restrict__ x, uint16_t* __restrict__ xp){
  constexpr int W=H, Hp=H+2, Wp=W+2, KB=C/32;
  int idx = blockIdx.x*256 + threadIdx.x;
  int total = 8*KB*Hp*Wp;
  if (idx >= total) return;
  int w = idx % Wp; int t2 = idx / Wp;
  int h = t2 % Hp;  int bk = t2 / Hp;
  const uint32_t key = (uint32_t)((w&7)<<4);
  char* dst = (char*)xp;
  size_t cbyte = (size_t)idx*64;
  if (h==0 || h==Hp-1 || w==0 || w==Wp-1){
    uint4 z = {0,0,0,0};
#pragma unroll
    for (int q=0;q<4;++q) *(uint4*)(dst + ((cbyte + (uint32_t)(q*16)) ^ key)) = z;
  } else {
    const int b = bk/KB, kb = bk - b*KB;
    const float* src = x + (((size_t)(b*C + kb*32)*H + (h-1))*W + (w-1));
#pragma unroll
    for (int q=0;q<4;++q){
      uint16_t tmp[8];
#pragma unroll
      for (int j=0;j<8;++j) tmp[j] = f2bf(src[(size_t)(q*8+j)*(H*W)]);
      *(uint4*)(dst + ((cbyte + (uint32_t)(q*16)) ^ key)) = *(uint4*)tmp;
    }
  }
}

// ---------------- zero border ring of a padded chunked buffer ----------------
template<int C,int H>
__global__ __launch_bounds__(256) void zero_border(uint16_t* __restrict__ yp){
  constexpr int Hp=H+2, Wp=H+2, KB=C/32;
  constexpr int NB = 2*Wp + 2*(Hp-2);
  int idx = blockIdx.x*256 + threadIdx.x;
  int total = 8*KB*NB;
  if (idx >= total) return;
  int j = idx % NB; int bk = idx / NB;
  int h, w;
  if (j < 2*Wp){ h = (j<Wp)?0:(Hp-1); w = j%Wp; }
  else { int j2 = j - 2*Wp; h = 1 + (j2 % (Hp-2)); w = (j2 < (Hp-2))?0:(Wp-1); }
  size_t chunk = ((size_t)bk*Hp + h)*Wp + w;
  const uint32_t key = (uint32_t)((w&7)<<4);
  uint4 z = {0,0,0,0};
  char* dst = (char*)yp;
#pragma unroll
  for (int q=0;q<4;++q) *(uint4*)(dst + ((chunk*64 + (uint32_t)(q*16)) ^ key)) = z;
}

// ---------------- 3x3 conv + bias + relu, 16x16x32 MFMA ----------------
// block: 128co x 160sp (TH=4 x TW=40), 4 waves, wave = 64co x 80sp = 4mi x 5ni of 16x16.
// acc = 80 VGPR/wave -> 3 waves/SIMD. Weights stream global->reg (marching ptr, 1-tap prefetch).
template<int C,int H,bool PADOUT>
__device__ __forceinline__ void conv_body(int lbid,
    const uint16_t* __restrict__ in, const uint16_t* __restrict__ wq,
    const float* __restrict__ bias, uint16_t* __restrict__ out, char* lds)
{
  constexpr int W=H, Hp=H+2, Wp=W+2, KB=C/32, TW=40, TH=4;
  constexpr int COB=128, F16B=C/16;
  constexpr int R=TH+2, ROWB=42*64, BUF=R*ROWB, NT=R*3, WAVES=4;
  constexpr int TAPSTRIDE = F16B*1024;
  const int tid = threadIdx.x, lane = tid&63, wave = tid>>6;
  const int wm = wave>>1, wn = wave&1;
  const int l15 = lane&15, h2 = lane>>4;

  int t = lbid;
  const int cb = t % (C/COB); t /= (C/COB);
  const int wt = t % (W/TW);  t /= (W/TW);
  const int ht = t % (H/TH);
  const int b  = t / (H/TH);
  const int h0 = ht*TH, w0 = wt*TW;

  // per-lane B-frag LDS addresses (XOR folded over the full low field)
  int addrB[5][3];
#pragma unroll
  for (int ni=0; ni<5; ++ni){
    int s = wn*80 + ni*16 + l15;
    int th = s/40, tw = s - th*40;
#pragma unroll
    for (int dw=0; dw<3; ++dw){
      int col = tw + dw;
      addrB[ni][dw] = th*ROWB + ((col*64 + h2*16) ^ ((col&7)<<4));
    }
  }

  // weight marching pointer: [kb][tap][f16][lane][8]; wave owns f16 = cb*8 + wm*4 + mi
  const char* wp = (const char*)wq + (size_t)(cb*8 + wm*4)*1024 + (size_t)lane*16;

  f32x4 acc[4][5];
#pragma unroll
  for (int mi=0;mi<4;++mi)
#pragma unroll
    for (int ni=0;ni<5;++ni)
      acc[mi][ni] = (f32x4){0.f,0.f,0.f,0.f};

  short8 a_[4];
#pragma unroll
  for (int mi=0; mi<4; ++mi) a_[mi] = *(const short8*)(wp + mi*1024);
  wp += TAPSTRIDE;

  auto STAGE = [&](int bi, int kb){
    const char* src = (const char*)(in + ((size_t)(b*KB + kb)*Hp + h0)*((size_t)Wp*32) + (size_t)w0*32);
    for (int tt = wave; tt < NT; tt += WAVES){
      int r = tt/3, k = tt - r*3;
      char* l = lds + bi*BUF + r*ROWB + k*1024;
      const char* g = src + (size_t)r*(Wp*64) + k*1024 + lane*16;
      if (k < 2 || lane < 40) gl_lds16(g, l);
    }
  };

  auto COMPUTE = [&](auto BC){
    constexpr int BI = decltype(BC)::value;
    const char* lb = lds + BI*BUF;
#pragma unroll
    for (int tap=0; tap<9; ++tap){
      const int dh = tap/3, dw = tap - dh*3;
      short8 an_[4];
#pragma unroll
      for (int mi=0;mi<4;++mi) an_[mi] = *(const short8*)(wp + mi*1024);
      wp += TAPSTRIDE;                       // marches across taps AND kb-steps
      short8 bf[5];
#pragma unroll
      for (int ni=0; ni<5; ++ni)
        bf[ni] = *(const short8*)(lb + addrB[ni][dw] + dh*ROWB);
#pragma unroll
      for (int ni=0; ni<5; ++ni)
#pragma unroll
        for (int mi=0; mi<4; ++mi)
          acc[mi][ni] = __builtin_amdgcn_mfma_f32_16x16x32_bf16(a_[mi], bf[ni], acc[mi][ni], 0,0,0);
#pragma unroll
      for (int mi=0;mi<4;++mi) a_[mi] = an_[mi];
    }
  };

  STAGE(0, 0);
  __syncthreads();
#pragma unroll 1
  for (int kb = 0; kb < KB; kb += 2){
    STAGE(1, kb+1);
    COMPUTE(IC<0>{});
    __syncthreads();
    if (kb+2 < KB) STAGE(0, kb+2);
    COMPUTE(IC<1>{});
    __syncthreads();
  }

  // epilogue: bias + relu + packed 8B swizzled chunk stores
#pragma unroll
  for (int mi=0; mi<4; ++mi){
    const int kbo = cb*4 + wm*2 + (mi>>1);
    const int cobase = kbo*32 + (mi&1)*16 + h2*4;
    const f32x4 bv = *(const f32x4*)(bias + cobase);
#pragma unroll
    for (int ni=0; ni<5; ++ni){
      const int s = wn*80 + ni*16 + l15;
      const int th = s/40, tw = s - th*40;
      size_t chunk; uint32_t key;
      if (PADOUT){
        const int hh = h0+th+1, ww = w0+tw+1;
        chunk = ((size_t)(b*KB + kbo)*Hp + hh)*Wp + ww;
        key = (uint32_t)((ww&7)<<4);
      } else {
        const int hh = h0+th, ww = w0+tw;
        chunk = ((size_t)(b*KB + kbo)*H + hh)*W + ww;
        key = (uint32_t)((ww&7)<<4);
      }
      float v0 = fmaxf(acc[mi][ni][0] + bv[0], 0.f);
      float v1 = fmaxf(acc[mi][ni][1] + bv[1], 0.f);
      float v2 = fmaxf(acc[mi][ni][2] + bv[2], 0.f);
      float v3 = fmaxf(acc[mi][ni][3] + bv[3], 0.f);
      uint2 dd;
      dd.x = (uint32_t)f2bf(v0) | ((uint32_t)f2bf(v1)<<16);
      dd.y = (uint32_t)f2bf(v2) | ((uint32_t)f2bf(v3)<<16);
      *(uint2*)((char*)out + ((chunk*64 + (uint32_t)((mi&1)*32 + h2*8)) ^ key)) = dd;
    }
  }
}

template<bool PADOUT>
__global__ __launch_bounds__(256, 3) void conv_all(int b45, int b34,
    const uint16_t* in5, const uint16_t* wq5, const float* bi5, uint16_t* o5,
    const uint16_t* in4, const uint16_t* wq4, const float* bi4, uint16_t* o4,
    const uint16_t* in3, const uint16_t* wq3, const float* bi3, uint16_t* o3)
{
  __shared__ __align__(16) char lds[2*6*2688];
  const int bid = blockIdx.x;
  if (bid < b45)      conv_body<512, 40, PADOUT>(bid,       in5, wq5, bi5, o5, lds);
  else if (bid < b34) conv_body<256, 80, PADOUT>(bid - b45, in4, wq4, bi4, o4, lds);
  else                conv_body<128,160, PADOUT>(bid - b34, in3, wq3, bi3, o3, lds);
}

// ---------------- final: 1x1 conv (5ch) + decode + sigmoid ----------------
template<int C,int H,int OFF,int STRIDE>
__global__ __launch_bounds__(256) void head_final(const uint16_t* __restrict__ y,
    const float* __restrict__ wf, const float* __restrict__ bfp, float* __restrict__ outp)
{
  constexpr int W=H, HW=H*W, KBo=C/32, S=33600;
  int idx = blockIdx.x*256 + threadIdx.x;
  if (idx >= 8*HW) return;
  const int b = idx/HW, sp = idx - b*HW;
  const int w = sp % W;
  const uint32_t key = (uint32_t)((w&7)<<4);
  float a0=bfp[0], a1=bfp[1], a2=bfp[2], a3=bfp[3], a4=bfp[4];
  const char* yb = (const char*)y;
  for (int kb=0; kb<KBo; ++kb){
    size_t cbyte = ((size_t)(b*KBo + kb)*HW + sp)*64;
#pragma unroll
    for (int q=0; q<4; ++q){
      uint4 u = *(const uint4*)(yb + ((cbyte + (uint32_t)(q*16)) ^ key));
      const uint16_t* pv = (const uint16_t*)&u;
#pragma unroll
      for (int j=0; j<8; ++j){
        float v = bf2f(pv[j]);
        int ci = kb*32 + q*8 + j;
        a0 += v*wf[0*C+ci]; a1 += v*wf[1*C+ci]; a2 += v*wf[2*C+ci];
        a3 += v*wf[3*C+ci]; a4 += v*wf[4*C+ci];
      }
    }
  }
  const float ax = (float)(sp % W) + 0.5f;
  const float ay = (float)(sp / W) + 0.5f;
  const float o0 = (ax + 0.5f*(a2-a0)) * (float)STRIDE;
  const float o1 = (ay + 0.5f*(a3-a1)) * (float)STRIDE;
  const float o2 = (a0+a2) * (float)STRIDE;
  const float o3 = (a1+a3) * (float)STRIDE;
  const float o4 = 1.0f/(1.0f + expf(-a4));
  float* ob = outp + (size_t)b*5*S + OFF + sp;
  ob[0*S]=o0; ob[1*S]=o1; ob[2*S]=o2; ob[3*S]=o3; ob[4*S]=o4;
}

extern "C" void kernel_launch(void* const* d_in, const int* in_sizes, int n_in,
                              void* d_out, int out_size, void* d_ws, size_t ws_size,
                              hipStream_t stream){
  (void)in_sizes; (void)n_in; (void)out_size;
  const float* x[3] = {(const float*)d_in[0], (const float*)d_in[1], (const float*)d_in[2]};
  const float *w1[3],*s1[3],*b1[3],*w2[3],*s2[3],*b2[3],*wf[3],*bfp[3];
  for (int h=0; h<3; ++h){
    const int base = 3 + h*8;
    w1[h]=(const float*)d_in[base+0]; s1[h]=(const float*)d_in[base+1];
    b1[h]=(const float*)d_in[base+2]; w2[h]=(const float*)d_in[base+3];
    s2[h]=(const float*)d_in[base+4]; b2[h]=(const float*)d_in[base+5];
    wf[h]=(const float*)d_in[base+6]; bfp[h]=(const float*)d_in[base+7];
  }
  // h: 0=p3(C128,H160), 1=p4(C256,H80), 2=p5(C512,H40)
  static const int   Cs[3] = {128, 256, 512};
  static const size_t Wb[3] = {294912, 1179648, 4718592};
  static const size_t Ab[3] = {53747712, 27541504, 14450688};
  static const int   NB[3] = {1280, 640, 320};     // conv blocks per head (TH=4 tiling)
  float* out = (float*)d_out;
  char* ws = (char*)d_ws;

  size_t off = 0; size_t wOff[3][2];
  for (int h=0; h<3; ++h) for (int c=0; c<2; ++c){ wOff[h][c]=off; off += Wb[h]; }
  off = (off + 255) & ~(size_t)255;
  size_t aOff[3], bOff[3];
  for (int h=0; h<3; ++h){ aOff[h]=off; off += Ab[h]; }
  for (int h=0; h<3; ++h){ bOff[h]=off; off += Ab[h]; }
  const size_t fusedNeed = off;

  const size_t seqA = (2*4718592 + 255) & ~(size_t)255;
  const size_t seqB = seqA + 53747712;
  const size_t seqNeed = seqB + 53747712;

  if (ws_size >= fusedNeed){
    for (int h=0; h<3; ++h){
      int blocks = (Cs[h]/32)*(Cs[h]/16);
      prep_w2<<<blocks, 256, 0, stream>>>(w1[h], s1[h], (uint16_t*)(ws+wOff[h][0]), Cs[h]);
      prep_w2<<<blocks, 256, 0, stream>>>(w2[h], s2[h], (uint16_t*)(ws+wOff[h][1]), Cs[h]);
    }
    pad_in<128,160><<<3281, 256, 0, stream>>>(x[0], (uint16_t*)(ws+aOff[0]));
    pad_in<256, 80><<<1681, 256, 0, stream>>>(x[1], (uint16_t*)(ws+aOff[1]));
    pad_in<512, 40><<< 882, 256, 0, stream>>>(x[2], (uint16_t*)(ws+aOff[2]));
    zero_border<128,160><<<81, 256, 0, stream>>>((uint16_t*)(ws+bOff[0]));
    zero_border<256, 80><<<81, 256, 0, stream>>>((uint16_t*)(ws+bOff[1]));
    zero_border<512, 40><<<82, 256, 0, stream>>>((uint16_t*)(ws+bOff[2]));
    const int b45 = NB[2], b34 = NB[2]+NB[1], grid = NB[2]+NB[1]+NB[0];
    conv_all<true><<<grid, 256, 0, stream>>>(b45, b34,
      (const uint16_t*)(ws+aOff[2]), (const uint16_t*)(ws+wOff[2][0]), b1[2], (uint16_t*)(ws+bOff[2]),
      (const uint16_t*)(ws+aOff[1]), (const uint16_t*)(ws+wOff[1][0]), b1[1], (uint16_t*)(ws+bOff[1]),
      (const uint16_t*)(ws+aOff[0]), (const uint16_t*)(ws+wOff[0][0]), b1[0], (uint16_t*)(ws+bOff[0]));
    conv_all<false><<<grid, 256, 0, stream>>>(b45, b34,
      (const uint16_t*)(ws+bOff[2]), (const uint16_t*)(ws+wOff[2][1]), b2[2], (uint16_t*)(ws+aOff[2]),
      (const uint16_t*)(ws+bOff[1]), (const uint16_t*)(ws+wOff[1][1]), b2[1], (uint16_t*)(ws+aOff[1]),
      (const uint16_t*)(ws+bOff[0]), (const uint16_t*)(ws+wOff[0][1]), b2[0], (uint16_t*)(ws+aOff[0]));
    head_final<128,160,     0,  8><<<800, 256, 0, stream>>>((const uint16_t*)(ws+aOff[0]), wf[0], bfp[0], out);
    head_final<256, 80, 25600, 16><<<200, 256, 0, stream>>>((const uint16_t*)(ws+aOff[1]), wf[1], bfp[1], out);
    head_final<512, 40, 32000, 32><<< 50, 256, 0, stream>>>((const uint16_t*)(ws+aOff[2]), wf[2], bfp[2], out);
  } else {
    if (ws_size < seqNeed) return;
    uint16_t* W1p = (uint16_t*)(ws + 0);
    uint16_t* W2p = (uint16_t*)(ws + 4718592);
    uint16_t* A   = (uint16_t*)(ws + seqA);
    uint16_t* B   = (uint16_t*)(ws + seqB);
    for (int h=0; h<3; ++h){
      int blocks = (Cs[h]/32)*(Cs[h]/16);
      prep_w2<<<blocks, 256, 0, stream>>>(w1[h], s1[h], W1p, Cs[h]);
      prep_w2<<<blocks, 256, 0, stream>>>(w2[h], s2[h], W2p, Cs[h]);
      int grid = NB[h];
      int b45, b34;
      if (h==2){ b45=grid; b34=grid; } else if (h==1){ b45=0; b34=grid; } else { b45=0; b34=0; }
      if (h==0){
        pad_in<128,160><<<3281,256,0,stream>>>(x[0], A);
        zero_border<128,160><<<81,256,0,stream>>>(B);
      } else if (h==1){
        pad_in<256,80><<<1681,256,0,stream>>>(x[1], A);
        zero_border<256,80><<<81,256,0,stream>>>(B);
      } else {
        pad_in<512,40><<<882,256,0,stream>>>(x[2], A);
        zero_border<512,40><<<82,256,0,stream>>>(B);
      }
      conv_all<true><<<grid, 256, 0, stream>>>(b45, b34,
        A, W1p, b1[h], B,  A, W1p, b1[h], B,  A, W1p, b1[h], B);
      conv_all<false><<<grid, 256, 0, stream>>>(b45, b34,
        B, W2p, b2[h], A,  B, W2p, b2[h], A,  B, W2p, b2[h], A);
      if (h==0)      head_final<128,160,     0,  8><<<800,256,0,stream>>>(A, wf[0], bfp[0], out);
      else if (h==1) head_final<256, 80, 25600, 16><<<200,256,0,stream>>>(A, wf[1], bfp[1], out);
      else           head_final<512, 40, 32000, 32><<< 50,256,0,stream>>>(A, wf[2], bfp[2], out);
    }
  }
}